// Round 1
// baseline (625.483 us; speedup 1.0000x reference)
//
#include <hip/hip_runtime.h>
#include <math.h>

#define NUMCH 65
#define THREADS 256
#define TPT 8
#define TILE_T (THREADS * TPT)   // 2048
#define CHUNK 512
#define NGROUPS 32
#define SEG (TILE_T + CHUNK + 16)
#define MAXP 160

struct PieceMap {
  int c[MAXP];
  unsigned char pidx[MAXP];
  unsigned char pcnt[MAXP];
  int start[NGROUPS + 1];
};

// Find first nonzero tap per channel (weights are front-zero-padded).
__global__ void k0_scan_kernel(const float* __restrict__ w, int K, int* __restrict__ k0out)
{
  int c = blockIdx.x;
  __shared__ int s_min;
  if (threadIdx.x == 0) s_min = K;
  __syncthreads();
  const float* wc = w + (size_t)c * K;
  int local = K;
  for (int k = threadIdx.x; k < K; k += blockDim.x) {
    if (wc[k] != 0.0f) { local = k; break; }
  }
  atomicMin(&s_min, local);
  __syncthreads();
  if (threadIdx.x == 0) k0out[c] = s_min;
}

__global__ void zero_kernel(float* __restrict__ out, int n)
{
  int i = blockIdx.x * blockDim.x + threadIdx.x;
  if (i < n) out[i] = 0.0f;
}

// out[b,t] = (1/fs) * sum_c sum_k x[b,c, t + start_c - (K-1) + k] * w[c,k]
__global__ __launch_bounds__(THREADS)
void conv_gather_kernel(const float* __restrict__ inp, const float* __restrict__ w,
                        const int* __restrict__ gidx, const int* __restrict__ fsp,
                        const int* __restrict__ k0arr, float* __restrict__ out,
                        PieceMap pm, int B, int T, int K)
{
  __shared__ float xs[SEG];
  const int g = blockIdx.x, tile = blockIdx.y, b = blockIdx.z;
  const int tid = threadIdx.x;
  const int tileBase = tile * TILE_T;
  const int q0 = tid * TPT;
  const int Kv = K & ~3;

  float acc[TPT];
  #pragma unroll
  for (int j = 0; j < TPT; ++j) acc[j] = 0.0f;

  for (int ci = pm.start[g]; ci < pm.start[g + 1]; ++ci) {
    const int c  = pm.c[ci];
    const int pi = pm.pidx[ci];
    const int pc = pm.pcnt[ci];
    const int start_c = gidx[(size_t)c * T];   // gather_idx[c,0]
    const int off = start_c - (K - 1);
    const int k0 = k0arr[c];
    const int kstart = k0 & ~3;
    const int lenv = Kv - kstart;
    const int pieceLen = ((lenv / pc) + 3) & ~3;
    int ka = kstart + pi * pieceLen;
    if (ka > Kv) ka = Kv;
    const int kb = (pi == pc - 1) ? K : min(Kv, ka + pieceLen);
    const float* __restrict__ xc = inp + ((size_t)b * (2 * NUMCH) + c) * T;
    const float* __restrict__ wc = w + (size_t)c * K;

    for (int kc = ka; kc < kb; kc += CHUNK) {
      const int lim  = min(CHUNK, kb - kc);
      const int limv = lim & ~3;
      const int segBase = tileBase + off + kc;
      // stage x segment into LDS (zero outside [0,T))
      for (int s = tid; s < SEG; s += THREADS) {
        int gi = segBase + s;
        xs[s] = (gi >= 0 && gi < T) ? xc[gi] : 0.0f;
      }
      __syncthreads();

      // sliding 12-float register window; 32 FMAs per ds_read_b128
      float xw[12];
      #pragma unroll
      for (int m = 0; m < 12; ++m) xw[m] = xs[q0 + m];

      for (int kk = 0; kk < limv; kk += 4) {
        const float4 w4 = *(const float4*)(wc + kc + kk);  // uniform -> s_load
        const float wv[4] = {w4.x, w4.y, w4.z, w4.w};
        #pragma unroll
        for (int dk = 0; dk < 4; ++dk) {
          #pragma unroll
          for (int j = 0; j < TPT; ++j)
            acc[j] = fmaf(xw[j + dk], wv[dk], acc[j]);
        }
        #pragma unroll
        for (int m = 0; m < 8; ++m) xw[m] = xw[m + 4];
        const float4 nx = *(const float4*)(&xs[q0 + kk + 12]);
        xw[8] = nx.x; xw[9] = nx.y; xw[10] = nx.z; xw[11] = nx.w;
      }
      // scalar tail (K % 4 remainder, last chunk of last piece only)
      for (int kk = limv; kk < lim; ++kk) {
        const float wv = wc[kc + kk];
        #pragma unroll
        for (int j = 0; j < TPT; ++j)
          acc[j] = fmaf(xs[q0 + kk + j], wv, acc[j]);
      }
      __syncthreads();
    }
  }

  const float inv_fs = 1.0f / (float)fsp[0];
  float* op = out + (size_t)b * T + tileBase + q0;
  #pragma unroll
  for (int j = 0; j < TPT; ++j)
    atomicAdd(&op[j], acc[j] * inv_fs);
}

extern "C" void kernel_launch(void* const* d_in, const int* in_sizes, int n_in,
                              void* d_out, int out_size, void* d_ws, size_t ws_size,
                              hipStream_t stream)
{
  const float* inp = (const float*)d_in[0];
  const float* wgt = (const float*)d_in[1];
  const int* gidx  = (const int*)d_in[2];
  const int* fsp   = (const int*)d_in[3];
  float* out = (float*)d_out;
  int* k0arr = (int*)d_ws;

  const int K = in_sizes[1] / NUMCH;
  const int T = in_sizes[2] / NUMCH;
  const int B = in_sizes[0] / (2 * NUMCH * T);

  // --- host-side deterministic load-balance: split channels into k-pieces,
  //     greedy-bin pieces into NGROUPS groups by analytic gammatone length ---
  PieceMap pm;
  double work[NUMCH];
  double total = 0.0;
  for (int c = 0; c < NUMCH; ++c) { work[c] = pow(10.0, (32.0 - c) / 32.0); total += work[c]; }
  const double target = total / NGROUPS;

  int pC[MAXP], pI[MAXP], pN[MAXP];
  double pW[MAXP];
  int np_ = 0;
  for (int c = 0; c < NUMCH; ++c) {
    int pc = (int)ceil(work[c] / target);
    if (pc < 1) pc = 1;
    if (pc > 8) pc = 8;
    for (int i = 0; i < pc && np_ < MAXP; ++i) {
      pC[np_] = c; pI[np_] = i; pN[np_] = pc; pW[np_] = work[c] / pc; ++np_;
    }
  }
  // insertion sort by descending work
  for (int i = 1; i < np_; ++i) {
    int c = pC[i], pi = pI[i], pn = pN[i];
    double wv = pW[i];
    int j = i - 1;
    while (j >= 0 && pW[j] < wv) {
      pC[j+1] = pC[j]; pI[j+1] = pI[j]; pN[j+1] = pN[j]; pW[j+1] = pW[j]; --j;
    }
    pC[j+1] = c; pI[j+1] = pi; pN[j+1] = pn; pW[j+1] = wv;
  }
  // greedy bin
  double gsum[NGROUPS];
  int gcnt[NGROUPS];
  static int glist[NGROUPS][MAXP];
  for (int g = 0; g < NGROUPS; ++g) { gsum[g] = 0.0; gcnt[g] = 0; }
  for (int i = 0; i < np_; ++i) {
    int best = 0;
    for (int g = 1; g < NGROUPS; ++g) if (gsum[g] < gsum[best]) best = g;
    glist[best][gcnt[best]++] = i;
    gsum[best] += pW[i];
  }
  int p = 0;
  pm.start[0] = 0;
  for (int g = 0; g < NGROUPS; ++g) {
    for (int i = 0; i < gcnt[g]; ++i) {
      int id = glist[g][i];
      pm.c[p] = pC[id];
      pm.pidx[p] = (unsigned char)pI[id];
      pm.pcnt[p] = (unsigned char)pN[id];
      ++p;
    }
    pm.start[g + 1] = p;
  }
  for (int i = p; i < MAXP; ++i) { pm.c[i] = 0; pm.pidx[i] = 0; pm.pcnt[i] = 1; }

  k0_scan_kernel<<<NUMCH, 256, 0, stream>>>(wgt, K, k0arr);
  zero_kernel<<<(out_size + 255) / 256, 256, 0, stream>>>(out, out_size);
  dim3 grid(NGROUPS, T / TILE_T, B);
  conv_gather_kernel<<<grid, THREADS, 0, stream>>>(inp, wgt, gidx, fsp, k0arr, out, pm, B, T, K);
}